// Round 1
// baseline (459.276 us; speedup 1.0000x reference)
//
#include <hip/hip_runtime.h>

typedef __bf16 bf16;
typedef __bf16 bf16x8 __attribute__((ext_vector_type(8)));
typedef float f32x4 __attribute__((ext_vector_type(4)));

#define GLOAD16(g, l)                                                        \
  __builtin_amdgcn_global_load_lds(                                          \
      (const __attribute__((address_space(1))) void*)(g),                    \
      (__attribute__((address_space(3))) void*)(l), 16, 0, 0)

// ---------------- cast fp32 -> bf16 (optionally scaled) ----------------
__global__ void cast_f32_to_bf16(const float* __restrict__ in,
                                 bf16* __restrict__ out, int n8, float scale) {
  int i = blockIdx.x * blockDim.x + threadIdx.x;
  if (i >= n8) return;
  const float4* p = reinterpret_cast<const float4*>(in) + (size_t)i * 2;
  float4 a = p[0], b = p[1];
  bf16x8 o;
  o[0] = (bf16)(a.x * scale); o[1] = (bf16)(a.y * scale);
  o[2] = (bf16)(a.z * scale); o[3] = (bf16)(a.w * scale);
  o[4] = (bf16)(b.x * scale); o[5] = (bf16)(b.y * scale);
  o[6] = (bf16)(b.z * scale); o[7] = (bf16)(b.w * scale);
  *reinterpret_cast<bf16x8*>(out + (size_t)i * 8) = o;
}

// ---------------- NT GEMM: C[M,N] = A[M,K] * B[N,K]^T (m97 structure) --------
// 128x128 tile, 4 waves, BK=32, global_load_lds(16B) staging.
template <typename OT>
__global__ __launch_bounds__(256) void gemm_nt(
    const bf16* __restrict__ A, const bf16* __restrict__ B, OT* __restrict__ C,
    int M, int N, int K, int lda, int ldb, int ldc) {
  (void)M; (void)N;
  __shared__ bf16 As[128 * 32];
  __shared__ bf16 Bs[128 * 32];
  const int t = threadIdx.x;
  const int w = t >> 6, lane = t & 63;
  const int l15 = lane & 15, l4 = lane >> 4;
  const int wr = w >> 1, wc = w & 1;
  const int m0 = blockIdx.y * 128, n0 = blockIdx.x * 128;
  const int srow = t >> 2, scol = (t & 3) * 8;
  f32x4 acc[4][4] = {};
  for (int k0 = 0; k0 < K; k0 += 32) {
    __syncthreads();
#pragma unroll
    for (int i = 0; i < 2; i++) {
      GLOAD16(A + (size_t)(m0 + i * 64 + srow) * lda + k0 + scol,
              As + i * 2048 + w * 512);
      GLOAD16(B + (size_t)(n0 + i * 64 + srow) * ldb + k0 + scol,
              Bs + i * 2048 + w * 512);
    }
    __syncthreads();
    bf16x8 af[4], bfr[4];
#pragma unroll
    for (int m = 0; m < 4; m++)
      af[m] = *reinterpret_cast<const bf16x8*>(As + (wr * 64 + m * 16 + l15) * 32 + l4 * 8);
#pragma unroll
    for (int n = 0; n < 4; n++)
      bfr[n] = *reinterpret_cast<const bf16x8*>(Bs + (wc * 64 + n * 16 + l15) * 32 + l4 * 8);
#pragma unroll
    for (int m = 0; m < 4; m++)
#pragma unroll
      for (int n = 0; n < 4; n++)
        acc[m][n] = __builtin_amdgcn_mfma_f32_16x16x32_bf16(af[m], bfr[n], acc[m][n], 0, 0, 0);
  }
#pragma unroll
  for (int m = 0; m < 4; m++)
#pragma unroll
    for (int n = 0; n < 4; n++)
#pragma unroll
      for (int j = 0; j < 4; j++) {
        int row = m0 + wr * 64 + m * 16 + l4 * 4 + j;
        int col = n0 + wc * 64 + n * 16 + l15;
        C[(size_t)row * ldc + col] = (OT)acc[m][n][j];
      }
}

// ---------------- fused flash attention ----------------
// grid: (sq_tiles=32, b*16+h=32). block = 256 (4 waves x 16 sq rows).
// Q: [r=s*2+b, 2048] bf16 (pre-scaled). K: same layout. Vt: [b*2048+h*128+d, s].
__global__ __launch_bounds__(256) void attn_fwd(
    const bf16* __restrict__ Q, const bf16* __restrict__ Kb,
    const bf16* __restrict__ Vt, bf16* __restrict__ O) {
  __shared__ bf16 Ks[64 * 128];   // logical [sk][d], swizzled
  __shared__ bf16 Vs[128 * 64];   // logical [d][sk], swizzled
  __shared__ bf16 Ps[4 * 16 * 64];// per-wave [sq][sk], swizzled
  const int t = threadIdx.x, w = t >> 6, lane = t & 63;
  const int l15 = lane & 15, l4 = lane >> 4;
  const int sq0 = blockIdx.x * 64;
  const int bh = blockIdx.y;
  const int b = bh >> 4, h = bh & 15;
  const size_t hoff = (size_t)h * 128;

  // hoist Q fragments to registers (A-frag: row=l15, k=c*32+l4*8)
  bf16x8 qf[4];
  {
    const bf16* qp = Q + ((size_t)(sq0 + w * 16 + l15) * 2 + b) * 2048 + hoff;
#pragma unroll
    for (int c = 0; c < 4; c++)
      qf[c] = *reinterpret_cast<const bf16x8*>(qp + c * 32 + l4 * 8);
  }
  f32x4 po[8] = {};
  float m_run[4] = {-3e38f, -3e38f, -3e38f, -3e38f};
  float l_run[4] = {0.f, 0.f, 0.f, 0.f};

  for (int sk0 = 0; sk0 < 2048; sk0 += 64) {
    __syncthreads();
    // stage K tile [64][128]: pre-swizzled global source, linear LDS dest
#pragma unroll
    for (int i = 0; i < 4; i++) {
      int sB = ((i * 256 + t) * 8) * 2;       // stored byte offset
      int row = sB >> 8;
      int lB = sB ^ ((row & 7) << 4);         // logical byte
      int ge = lB >> 1;
      int gr = ge >> 7, gc = ge & 127;
      GLOAD16(Kb + ((size_t)(sk0 + gr) * 2 + b) * 2048 + hoff + gc,
              Ks + i * 2048 + w * 512);
    }
    // stage Vt tile [128][64]
#pragma unroll
    for (int i = 0; i < 4; i++) {
      int sB = ((i * 256 + t) * 8) * 2;
      int row = sB >> 7;
      int lB = sB ^ ((row & 7) << 4);
      int ge = lB >> 1;
      int gr = ge >> 6, gc = ge & 63;
      GLOAD16(Vt + ((size_t)(b * 2048) + hoff + gr) * 2048 + sk0 + gc,
              Vs + i * 2048 + w * 512);
    }
    __syncthreads();

    // QK^T: 16 MFMAs -> sc[n] rows=(l4*4+j), cols=n*16+l15
    f32x4 sc[4] = {};
#pragma unroll
    for (int c = 0; c < 4; c++)
#pragma unroll
      for (int n = 0; n < 4; n++) {
        int krow = n * 16 + l15;
        int kB = (krow << 8) + ((c * 32 + l4 * 8) << 1);
        kB ^= (krow & 7) << 4;
        bf16x8 kf = *reinterpret_cast<const bf16x8*>(
            reinterpret_cast<const char*>(Ks) + kB);
        sc[n] = __builtin_amdgcn_mfma_f32_16x16x32_bf16(qf[c], kf, sc[n], 0, 0, 0);
      }

    // online softmax over 64 cols; rows owned by 16-lane groups
    float mx[4], f[4], rs[4];
#pragma unroll
    for (int j = 0; j < 4; j++)
      mx[j] = fmaxf(fmaxf(sc[0][j], sc[1][j]), fmaxf(sc[2][j], sc[3][j]));
#pragma unroll
    for (int d = 1; d < 16; d <<= 1)
#pragma unroll
      for (int j = 0; j < 4; j++) mx[j] = fmaxf(mx[j], __shfl_xor(mx[j], d));
#pragma unroll
    for (int j = 0; j < 4; j++) {
      float mn = fmaxf(m_run[j], mx[j]);
      f[j] = __expf(m_run[j] - mn);
      m_run[j] = mn;
      rs[j] = 0.f;
    }
#pragma unroll
    for (int n = 0; n < 4; n++)
#pragma unroll
      for (int j = 0; j < 4; j++) {
        float p = __expf(sc[n][j] - m_run[j]);
        rs[j] += p;
        int prow = l4 * 4 + j;
        int pB = (w * 2048 + prow * 128 + (n * 16 + l15) * 2) ^ ((prow & 7) << 4);
        *reinterpret_cast<bf16*>(reinterpret_cast<char*>(Ps) + pB) = (bf16)p;
      }
#pragma unroll
    for (int d = 1; d < 16; d <<= 1)
#pragma unroll
      for (int j = 0; j < 4; j++) rs[j] += __shfl_xor(rs[j], d);
#pragma unroll
    for (int j = 0; j < 4; j++) l_run[j] = l_run[j] * f[j] + rs[j];
#pragma unroll
    for (int n = 0; n < 8; n++)
#pragma unroll
      for (int j = 0; j < 4; j++) po[n][j] *= f[j];

    // PV: A-frags from Ps (same wave, no barrier needed), B-frags from Vs
    bf16x8 pf[2];
#pragma unroll
    for (int kk = 0; kk < 2; kk++) {
      int pB = (w * 2048 + l15 * 128 + (kk * 32 + l4 * 8) * 2) ^ ((l15 & 7) << 4);
      pf[kk] = *reinterpret_cast<const bf16x8*>(
          reinterpret_cast<const char*>(Ps) + pB);
    }
#pragma unroll
    for (int n = 0; n < 8; n++)
#pragma unroll
      for (int kk = 0; kk < 2; kk++) {
        int vrow = n * 16 + l15;
        int vB = (vrow << 7) + ((kk * 32 + l4 * 8) << 1);
        vB ^= (vrow & 7) << 4;
        bf16x8 vf = *reinterpret_cast<const bf16x8*>(
            reinterpret_cast<const char*>(Vs) + vB);
        po[n] = __builtin_amdgcn_mfma_f32_16x16x32_bf16(pf[kk], vf, po[n], 0, 0, 0);
      }
  }

  // epilogue: divide by row sum, store bf16 to attn buffer
#pragma unroll
  for (int n = 0; n < 8; n++)
#pragma unroll
    for (int j = 0; j < 4; j++) {
      int row = sq0 + w * 16 + l4 * 4 + j;
      O[((size_t)row * 2 + b) * 2048 + hoff + n * 16 + l15] =
          (bf16)(po[n][j] / l_run[j]);
    }
}

extern "C" void kernel_launch(void* const* d_in, const int* in_sizes, int n_in,
                              void* d_out, int out_size, void* d_ws,
                              size_t ws_size, hipStream_t stream) {
  (void)in_sizes; (void)n_in; (void)out_size; (void)ws_size;
  const float* x  = (const float*)d_in[0];
  const float* wq = (const float*)d_in[1];
  const float* wk = (const float*)d_in[2];
  const float* wv = (const float*)d_in[3];
  const float* wo = (const float*)d_in[4];
  float* out = (float*)d_out;
  char* ws = (char*)d_ws;
  // ws layout (bytes): xb@0 (16M, reused as attn), qb@16M, kb@32M, vt@48M, wb@64M (8M)
  bf16* xb   = (bf16*)(ws);
  bf16* qb   = (bf16*)(ws + (1u << 24));
  bf16* kb   = (bf16*)(ws + (2u << 24));
  bf16* vt   = (bf16*)(ws + (3u << 24));
  bf16* wb   = (bf16*)(ws + (4u << 24));
  bf16* attn = xb;
  const float SCALE = 0.08838834764831845f;  // 128^-0.5, folded into wq

  cast_f32_to_bf16<<<4096, 256, 0, stream>>>(x, xb, 8388608 / 8, 1.0f);

  dim3 g1(16, 32);  // N/128, M/128 for M=4096
  cast_f32_to_bf16<<<2048, 256, 0, stream>>>(wq, wb, 4194304 / 8, SCALE);
  gemm_nt<bf16><<<g1, 256, 0, stream>>>(xb, wb, qb, 4096, 2048, 2048, 2048, 2048, 2048);

  cast_f32_to_bf16<<<2048, 256, 0, stream>>>(wk, wb, 4194304 / 8, 1.0f);
  gemm_nt<bf16><<<g1, 256, 0, stream>>>(xb, wb, kb, 4096, 2048, 2048, 2048, 2048, 2048);

  // V transposed: vt[b*2048 + j][s] = sum_h wv[j][h] * x[(s*2+b)][h]
  cast_f32_to_bf16<<<2048, 256, 0, stream>>>(wv, wb, 4194304 / 8, 1.0f);
  dim3 g2(16, 16);
  gemm_nt<bf16><<<g2, 256, 0, stream>>>(wb, xb,        vt,           2048, 2048, 2048, 2048, 4096, 2048);
  gemm_nt<bf16><<<g2, 256, 0, stream>>>(wb, xb + 2048, vt + 4194304, 2048, 2048, 2048, 2048, 4096, 2048);

  dim3 ga(32, 32);
  attn_fwd<<<ga, 256, 0, stream>>>(qb, kb, vt, attn);

  cast_f32_to_bf16<<<2048, 256, 0, stream>>>(wo, wb, 4194304 / 8, 1.0f);
  gemm_nt<float><<<g1, 256, 0, stream>>>(attn, wb, out, 4096, 2048, 2048, 2048, 2048, 2048);
}

// Round 2
// 381.102 us; speedup vs baseline: 1.2051x; 1.2051x over previous
//
#include <hip/hip_runtime.h>

typedef __bf16 bf16;
typedef __bf16 bf16x8 __attribute__((ext_vector_type(8)));
typedef float f32x4 __attribute__((ext_vector_type(4)));
typedef float f32x16 __attribute__((ext_vector_type(16)));
typedef unsigned int uint;

#define GLOAD16(g, l)                                                        \
  __builtin_amdgcn_global_load_lds(                                          \
      (const __attribute__((address_space(1))) void*)(g),                    \
      (__attribute__((address_space(3))) void*)(l), 16, 0, 0)

__device__ inline uint pack_bf16(float a, float b) {
  union { bf16 h[2]; uint u; } x;
  x.h[0] = (bf16)a; x.h[1] = (bf16)b;
  return x.u;
}

// ---------------- cast fp32 -> bf16 (optionally scaled) ----------------
__global__ void cast_f32_to_bf16(const float* __restrict__ in,
                                 bf16* __restrict__ out, int n8, float scale) {
  int i = blockIdx.x * blockDim.x + threadIdx.x;
  if (i >= n8) return;
  const float4* p = reinterpret_cast<const float4*>(in) + (size_t)i * 2;
  float4 a = p[0], b = p[1];
  bf16x8 o;
  o[0] = (bf16)(a.x * scale); o[1] = (bf16)(a.y * scale);
  o[2] = (bf16)(a.z * scale); o[3] = (bf16)(a.w * scale);
  o[4] = (bf16)(b.x * scale); o[5] = (bf16)(b.y * scale);
  o[6] = (bf16)(b.z * scale); o[7] = (bf16)(b.w * scale);
  *reinterpret_cast<bf16x8*>(out + (size_t)i * 8) = o;
}

// ---------------- NT GEMM: C[M,N] = A[M,K] * B[N,K]^T (m97 structure) --------
template <typename OT>
__global__ __launch_bounds__(256) void gemm_nt(
    const bf16* __restrict__ A, const bf16* __restrict__ B, OT* __restrict__ C,
    int M, int N, int K, int lda, int ldb, int ldc) {
  (void)M; (void)N;
  __shared__ bf16 As[128 * 32];
  __shared__ bf16 Bs[128 * 32];
  const int t = threadIdx.x;
  const int w = t >> 6, lane = t & 63;
  const int l15 = lane & 15, l4 = lane >> 4;
  const int wr = w >> 1, wc = w & 1;
  const int m0 = blockIdx.y * 128, n0 = blockIdx.x * 128;
  const int srow = t >> 2, scol = (t & 3) * 8;
  f32x4 acc[4][4] = {};
  for (int k0 = 0; k0 < K; k0 += 32) {
    __syncthreads();
#pragma unroll
    for (int i = 0; i < 2; i++) {
      GLOAD16(A + (size_t)(m0 + i * 64 + srow) * lda + k0 + scol,
              As + i * 2048 + w * 512);
      GLOAD16(B + (size_t)(n0 + i * 64 + srow) * ldb + k0 + scol,
              Bs + i * 2048 + w * 512);
    }
    __syncthreads();
    bf16x8 af[4], bfr[4];
#pragma unroll
    for (int m = 0; m < 4; m++)
      af[m] = *reinterpret_cast<const bf16x8*>(As + (wr * 64 + m * 16 + l15) * 32 + l4 * 8);
#pragma unroll
    for (int n = 0; n < 4; n++)
      bfr[n] = *reinterpret_cast<const bf16x8*>(Bs + (wc * 64 + n * 16 + l15) * 32 + l4 * 8);
#pragma unroll
    for (int m = 0; m < 4; m++)
#pragma unroll
      for (int n = 0; n < 4; n++)
        acc[m][n] = __builtin_amdgcn_mfma_f32_16x16x32_bf16(af[m], bfr[n], acc[m][n], 0, 0, 0);
  }
#pragma unroll
  for (int m = 0; m < 4; m++)
#pragma unroll
    for (int n = 0; n < 4; n++)
#pragma unroll
      for (int j = 0; j < 4; j++) {
        int row = m0 + wr * 64 + m * 16 + l4 * 4 + j;
        int col = n0 + wc * 64 + n * 16 + l15;
        C[(size_t)row * ldc + col] = (OT)acc[m][n][j];
      }
}

// ---------------- fused flash attention, 8-wave swapped-QK^T ----------------
// grid: (bh=32, sq_tiles=8). block = 512 (8 waves x 32 q-rows).
// Q/K: [r=s*2+b, 2048] bf16 (Q pre-scaled by SCALE*log2e). Vt: [b*2048+h*128+d, s].
// Swapped QK^T: mfma(A=K, B=Q) -> C[sk][q], q = lane&31 -> softmax row in-lane.
__global__ __launch_bounds__(512, 2) void attn_fwd(
    const bf16* __restrict__ Q, const bf16* __restrict__ Kb,
    const bf16* __restrict__ Vt, bf16* __restrict__ O) {
  __shared__ bf16 Ks[2][64 * 128];  // [sk][d], XOR-swizzled, 16KB each
  __shared__ bf16 Vs[2][128 * 64];  // [d][sk], XOR-swizzled, 16KB each
  const int t = threadIdx.x, w = t >> 6, lane = t & 63;
  const int l31 = lane & 31, half = lane >> 5;
  const int bh = blockIdx.x;
  const int b = bh >> 4, h = bh & 15;
  const int sq0 = blockIdx.y * 256 + w * 32;
  const size_t hoff = (size_t)h * 128;
  const size_t bO = (size_t)b * 2048 + hoff;  // Vt row base

  // Q fragments (B-operand): lane holds Q[sq0+l31][dc*16 + half*8 + j]
  bf16x8 qf[8];
  {
    const bf16* qp = Q + ((size_t)(sq0 + l31) * 2 + b) * 2048 + hoff + half * 8;
#pragma unroll
    for (int dc = 0; dc < 8; dc++)
      qf[dc] = *reinterpret_cast<const bf16x8*>(qp + dc * 16);
  }

  f32x16 acc_o[4] = {};            // C[q][d]: col=dcb*32+l31, row=srow(r)
  float m_run = -3e38f, l_run = 0.f;

  auto stage = [&](int nb, int sk0) {
#pragma unroll
    for (int i = 0; i < 2; i++) {
      int sB = (i * 512 + t) * 16;
      int row = sB >> 8;
      int ge = (sB ^ ((row & 7) << 4)) >> 1;
      GLOAD16(Kb + ((size_t)(sk0 + (ge >> 7)) * 2 + b) * 2048 + hoff + (ge & 127),
              Ks[nb] + (i * 512 + w * 64) * 8);
    }
#pragma unroll
    for (int i = 0; i < 2; i++) {
      int sB = (i * 512 + t) * 16;
      int row = sB >> 7;
      int ge = (sB ^ ((row & 7) << 4)) >> 1;
      GLOAD16(Vt + (bO + (ge >> 6)) * 2048 + sk0 + (ge & 63),
              Vs[nb] + (i * 512 + w * 64) * 8);
    }
  };

  stage(0, 0);

  for (int it = 0; it < 32; ++it) {
    const int cur = it & 1;
    __syncthreads();                       // drains vmcnt: tile `cur` ready
    if (it + 1 < 32) stage(cur ^ 1, (it + 1) * 64);

    const char* ksb = reinterpret_cast<const char*>(Ks[cur]);
    const char* vsb = reinterpret_cast<const char*>(Vs[cur]);

    // ---- QK^T: S[sk][q], sk = kt*32 + srow(r) ----
    f32x16 sc[2] = {};
    __builtin_amdgcn_s_setprio(1);
#pragma unroll
    for (int dc = 0; dc < 8; dc++) {
#pragma unroll
      for (int kt = 0; kt < 2; kt++) {
        int kB = (((kt * 32 + l31) << 8) + dc * 32 + half * 16) ^ ((l31 & 7) << 4);
        bf16x8 kf = *reinterpret_cast<const bf16x8*>(ksb + kB);
        sc[kt] = __builtin_amdgcn_mfma_f32_32x32x16_bf16(kf, qf[dc], sc[kt], 0, 0, 0);
      }
    }
    __builtin_amdgcn_s_setprio(0);

    // ---- online softmax (base-2), row q = l31 fully in lane(+partner) ----
    float pmax = -3e38f;
#pragma unroll
    for (int kt = 0; kt < 2; kt++)
#pragma unroll
      for (int r = 0; r < 16; r++) pmax = fmaxf(pmax, sc[kt][r]);
    pmax = fmaxf(pmax, __shfl_xor(pmax, 32));

    if (!__all(pmax - m_run <= 11.0f)) {   // defer-max (T13)
      float mn = fmaxf(m_run, pmax);
      float f = exp2f(m_run - mn);
      m_run = mn;
      l_run *= f;
#pragma unroll
      for (int idx = 0; idx < 16; idx++) {
        float fr = __shfl(f, (idx & 3) + 8 * (idx >> 2) + half * 4);
#pragma unroll
        for (int dcb = 0; dcb < 4; dcb++) acc_o[dcb][idx] *= fr;
      }
    }

    float rs = 0.f;
#pragma unroll
    for (int kt = 0; kt < 2; kt++)
#pragma unroll
      for (int r = 0; r < 16; r++) {
        float p = exp2f(sc[kt][r] - m_run);
        sc[kt][r] = p;
        rs += p;
      }
    rs += __shfl_xor(rs, 32);
    l_run += rs;

    // ---- P -> A-frags: word0..3 per skc via cross-half exchange ----
    // A-frag(skc): lane k = half*8+j; j0-3 from half0 holder regs 8s+0..3,
    // j4-7 from half1 holder same regs (s = skc&1, kt = skc>>1).
    uint pa[4][4];
#pragma unroll
    for (int skc = 0; skc < 4; skc++) {
      int kt = skc >> 1, s8 = (skc & 1) * 8;
      uint pk01 = pack_bf16(sc[kt][s8 + 0], sc[kt][s8 + 1]);
      uint pk23 = pack_bf16(sc[kt][s8 + 2], sc[kt][s8 + 3]);
      uint pk45 = pack_bf16(sc[kt][s8 + 4], sc[kt][s8 + 5]);
      uint pk67 = pack_bf16(sc[kt][s8 + 6], sc[kt][s8 + 7]);
      uint o01 = __shfl_xor(pk01, 32), o23 = __shfl_xor(pk23, 32);
      uint o45 = __shfl_xor(pk45, 32), o67 = __shfl_xor(pk67, 32);
      pa[skc][0] = half ? o45 : pk01;
      pa[skc][1] = half ? o67 : pk23;
      pa[skc][2] = half ? pk45 : o01;
      pa[skc][3] = half ? pk67 : o23;
    }

    // ---- PV: acc_o[dcb] += P(32q x 16sk) * V(16sk x 32d) ----
    __builtin_amdgcn_s_setprio(1);
#pragma unroll
    for (int dcb = 0; dcb < 4; dcb++) {
#pragma unroll
      for (int skc = 0; skc < 4; skc++) {
        int vB = (((dcb * 32 + l31) << 7) + skc * 32 + half * 16) ^ ((l31 & 7) << 4);
        bf16x8 vf = *reinterpret_cast<const bf16x8*>(vsb + vB);
        union { uint u[4]; bf16x8 v; } af;
        af.u[0] = pa[skc][0]; af.u[1] = pa[skc][1];
        af.u[2] = pa[skc][2]; af.u[3] = pa[skc][3];
        acc_o[dcb] = __builtin_amdgcn_mfma_f32_32x32x16_bf16(af.v, vf, acc_o[dcb], 0, 0, 0);
      }
    }
    __builtin_amdgcn_s_setprio(0);
  }

  // ---- epilogue: O[q][d] = acc / l_run ----
  float inv = 1.0f / l_run;
#pragma unroll
  for (int idx = 0; idx < 16; idx++) {
    int sr = (idx & 3) + 8 * (idx >> 2) + half * 4;
    float invr = __shfl(inv, sr);
    bf16* op = O + ((size_t)(sq0 + sr) * 2 + b) * 2048 + hoff + l31;
#pragma unroll
    for (int dcb = 0; dcb < 4; dcb++)
      op[dcb * 32] = (bf16)(acc_o[dcb][idx] * invr);
  }
}

extern "C" void kernel_launch(void* const* d_in, const int* in_sizes, int n_in,
                              void* d_out, int out_size, void* d_ws,
                              size_t ws_size, hipStream_t stream) {
  (void)in_sizes; (void)n_in; (void)out_size; (void)ws_size;
  const float* x  = (const float*)d_in[0];
  const float* wq = (const float*)d_in[1];
  const float* wk = (const float*)d_in[2];
  const float* wv = (const float*)d_in[3];
  const float* wo = (const float*)d_in[4];
  float* out = (float*)d_out;
  char* ws = (char*)d_ws;
  bf16* xb   = (bf16*)(ws);
  bf16* qb   = (bf16*)(ws + (1u << 24));
  bf16* kb   = (bf16*)(ws + (2u << 24));
  bf16* vt   = (bf16*)(ws + (3u << 24));
  bf16* wb   = (bf16*)(ws + (4u << 24));
  bf16* attn = xb;
  // softmax in base 2: fold log2(e) into the score scale
  const float SCALE = 0.08838834764831845f * 1.4426950408889634f;

  cast_f32_to_bf16<<<4096, 256, 0, stream>>>(x, xb, 8388608 / 8, 1.0f);

  dim3 g1(16, 32);  // N/128, M/128 for M=4096
  cast_f32_to_bf16<<<2048, 256, 0, stream>>>(wq, wb, 4194304 / 8, SCALE);
  gemm_nt<bf16><<<g1, 256, 0, stream>>>(xb, wb, qb, 4096, 2048, 2048, 2048, 2048, 2048);

  cast_f32_to_bf16<<<2048, 256, 0, stream>>>(wk, wb, 4194304 / 8, 1.0f);
  gemm_nt<bf16><<<g1, 256, 0, stream>>>(xb, wb, kb, 4096, 2048, 2048, 2048, 2048, 2048);

  cast_f32_to_bf16<<<2048, 256, 0, stream>>>(wv, wb, 4194304 / 8, 1.0f);
  dim3 g2(16, 16);
  gemm_nt<bf16><<<g2, 256, 0, stream>>>(wb, xb,        vt,           2048, 2048, 2048, 2048, 4096, 2048);
  gemm_nt<bf16><<<g2, 256, 0, stream>>>(wb, xb + 2048, vt + 4194304, 2048, 2048, 2048, 2048, 4096, 2048);

  dim3 ga(32, 8);  // x = bh (XCD-local KV reuse), y = q-tile
  attn_fwd<<<ga, 512, 0, stream>>>(qb, kb, vt, attn);

  cast_f32_to_bf16<<<2048, 256, 0, stream>>>(wo, wb, 4194304 / 8, 1.0f);
  gemm_nt<float><<<g1, 256, 0, stream>>>(attn, wb, out, 4096, 2048, 2048, 2048, 2048, 2048);
}

// Round 3
// 278.530 us; speedup vs baseline: 1.6489x; 1.3683x over previous
//
#include <hip/hip_runtime.h>

typedef __bf16 bf16;
typedef __bf16 bf16x8 __attribute__((ext_vector_type(8)));
typedef float f32x4 __attribute__((ext_vector_type(4)));
typedef float f32x16 __attribute__((ext_vector_type(16)));
typedef unsigned int uint;

#define GLOAD16(g, l)                                                        \
  __builtin_amdgcn_global_load_lds(                                          \
      (const __attribute__((address_space(1))) void*)(g),                    \
      (__attribute__((address_space(3))) void*)(l), 16, 0, 0)

__device__ inline uint pack_bf16(float a, float b) {
  union { bf16 h[2]; uint u; } x;
  x.h[0] = (bf16)a; x.h[1] = (bf16)b;
  return x.u;
}

// ---------------- cast fp32 -> bf16 (optionally scaled) ----------------
__global__ void cast_f32_to_bf16(const float* __restrict__ in,
                                 bf16* __restrict__ out, int n8, float scale) {
  int i = blockIdx.x * blockDim.x + threadIdx.x;
  if (i >= n8) return;
  const float4* p = reinterpret_cast<const float4*>(in) + (size_t)i * 2;
  float4 a = p[0], b = p[1];
  bf16x8 o;
  o[0] = (bf16)(a.x * scale); o[1] = (bf16)(a.y * scale);
  o[2] = (bf16)(a.z * scale); o[3] = (bf16)(a.w * scale);
  o[4] = (bf16)(b.x * scale); o[5] = (bf16)(b.y * scale);
  o[6] = (bf16)(b.z * scale); o[7] = (bf16)(b.w * scale);
  *reinterpret_cast<bf16x8*>(out + (size_t)i * 8) = o;
}

// ---------------- deep-pipelined NT GEMM ----------------
// C[M,N] = A[M,K] * B[N,K]^T. BM=256, BN=128, BK=64. 8 waves (4M x 2N),
// 3-stage LDS ring (48KB each), counted vmcnt (T4), raw barriers (1/K-tile),
// XOR-swizzled LDS (T2, (row&7)<<4 via pre-swizzled global source), setprio (T5).
template <typename OT>
__global__ __launch_bounds__(512, 2) void gemm_nt_256(
    const bf16* __restrict__ A, const bf16* __restrict__ B, OT* __restrict__ C,
    int K, int lda, int ldb, int ldc, long bsB, long bsC) {
  extern __shared__ char sh[];
  const int t = threadIdx.x;
  const int w = t >> 6, lane = t & 63;
  const int l15 = lane & 15, l4 = lane >> 4;
  const int wr = w >> 1, wc = w & 1;
  const int m0 = blockIdx.y * 256;
  const int n0 = blockIdx.x * 128;
  const bf16* Bg = B + (size_t)blockIdx.z * bsB;
  OT* Cg = C + (size_t)blockIdx.z * bsC;

  // staging: thread slot i -> stored byte sB=(i*512+t)*16; rows are 128B;
  // logical byte = sB ^ ((row&7)<<4)  (same involution applied on read)
  int sRow[4], sCol[4];
#pragma unroll
  for (int i = 0; i < 4; i++) {
    int sB_ = (i * 512 + t) * 16;
    int row = sB_ >> 7;
    int ge = (sB_ ^ ((row & 7) << 4)) >> 1;
    sRow[i] = ge >> 6;
    sCol[i] = ge & 63;
  }

  const int NT = K >> 6;
  f32x4 acc[4][4] = {};

  auto stage = [&](int tt) {
    char* dst = sh + (size_t)(tt % 3) * 49152;
    const int k0 = tt * 64;
#pragma unroll
    for (int i = 0; i < 4; i++)
      GLOAD16(A + (size_t)(m0 + sRow[i]) * lda + k0 + sCol[i],
              dst + (i * 512 + w * 64) * 16);
#pragma unroll
    for (int i = 0; i < 2; i++)
      GLOAD16(Bg + (size_t)(n0 + sRow[i]) * ldb + k0 + sCol[i],
              dst + 32768 + (i * 512 + w * 64) * 16);
  };

  auto compute = [&](int tt) {
    const char* Ab = sh + (size_t)(tt % 3) * 49152;
    const char* Bb = Ab + 32768;
    bf16x8 bfr[4][2];
#pragma unroll
    for (int n = 0; n < 4; n++)
#pragma unroll
      for (int kk = 0; kk < 2; kk++) {
        int row = wc * 64 + n * 16 + l15;
        int off = (row * 128 + kk * 64 + l4 * 16) ^ ((row & 7) << 4);
        bfr[n][kk] = *reinterpret_cast<const bf16x8*>(Bb + off);
      }
#pragma unroll
    for (int mh = 0; mh < 2; mh++) {
      bf16x8 af[2][2];
#pragma unroll
      for (int m = 0; m < 2; m++)
#pragma unroll
        for (int kk = 0; kk < 2; kk++) {
          int row = wr * 64 + (mh * 2 + m) * 16 + l15;
          int off = (row * 128 + kk * 64 + l4 * 16) ^ ((row & 7) << 4);
          af[m][kk] = *reinterpret_cast<const bf16x8*>(Ab + off);
        }
      __builtin_amdgcn_s_setprio(1);
#pragma unroll
      for (int m = 0; m < 2; m++)
#pragma unroll
        for (int n = 0; n < 4; n++)
#pragma unroll
          for (int kk = 0; kk < 2; kk++)
            acc[mh * 2 + m][n] = __builtin_amdgcn_mfma_f32_16x16x32_bf16(
                af[m][kk], bfr[n][kk], acc[mh * 2 + m][n], 0, 0, 0);
      __builtin_amdgcn_s_setprio(0);
    }
  };

  stage(0);
  stage(1);
  for (int tt = 0; tt < NT - 1; ++tt) {
    // tile tt's 6 loads must be landed; tile tt+1's 6 stay in flight (T4).
    asm volatile("s_waitcnt vmcnt(6)" ::: "memory");
    __builtin_amdgcn_s_barrier();
    if (tt + 2 < NT) stage(tt + 2);
    compute(tt);
  }
  asm volatile("s_waitcnt vmcnt(0)" ::: "memory");
  __builtin_amdgcn_s_barrier();
  compute(NT - 1);

#pragma unroll
  for (int m = 0; m < 4; m++)
#pragma unroll
    for (int n = 0; n < 4; n++)
#pragma unroll
      for (int j = 0; j < 4; j++) {
        int row = m0 + wr * 64 + m * 16 + l4 * 4 + j;
        int col = n0 + wc * 64 + n * 16 + l15;
        Cg[(size_t)row * ldc + col] = (OT)acc[m][n][j];
      }
}

// ---------------- fused flash attention, 8-wave swapped-QK^T (unchanged r2) --
__global__ __launch_bounds__(512, 2) void attn_fwd(
    const bf16* __restrict__ Q, const bf16* __restrict__ Kb,
    const bf16* __restrict__ Vt, bf16* __restrict__ O) {
  __shared__ bf16 Ks[2][64 * 128];
  __shared__ bf16 Vs[2][128 * 64];
  const int t = threadIdx.x, w = t >> 6, lane = t & 63;
  const int l31 = lane & 31, half = lane >> 5;
  const int bh = blockIdx.x;
  const int b = bh >> 4, h = bh & 15;
  const int sq0 = blockIdx.y * 256 + w * 32;
  const size_t hoff = (size_t)h * 128;
  const size_t bO = (size_t)b * 2048 + hoff;

  bf16x8 qf[8];
  {
    const bf16* qp = Q + ((size_t)(sq0 + l31) * 2 + b) * 2048 + hoff + half * 8;
#pragma unroll
    for (int dc = 0; dc < 8; dc++)
      qf[dc] = *reinterpret_cast<const bf16x8*>(qp + dc * 16);
  }

  f32x16 acc_o[4] = {};
  float m_run = -3e38f, l_run = 0.f;

  auto stage = [&](int nb, int sk0) {
#pragma unroll
    for (int i = 0; i < 2; i++) {
      int sB = (i * 512 + t) * 16;
      int row = sB >> 8;
      int ge = (sB ^ ((row & 7) << 4)) >> 1;
      GLOAD16(Kb + ((size_t)(sk0 + (ge >> 7)) * 2 + b) * 2048 + hoff + (ge & 127),
              Ks[nb] + (i * 512 + w * 64) * 8);
    }
#pragma unroll
    for (int i = 0; i < 2; i++) {
      int sB = (i * 512 + t) * 16;
      int row = sB >> 7;
      int ge = (sB ^ ((row & 7) << 4)) >> 1;
      GLOAD16(Vt + (bO + (ge >> 6)) * 2048 + sk0 + (ge & 63),
              Vs[nb] + (i * 512 + w * 64) * 8);
    }
  };

  stage(0, 0);

  for (int it = 0; it < 32; ++it) {
    const int cur = it & 1;
    __syncthreads();
    if (it + 1 < 32) stage(cur ^ 1, (it + 1) * 64);

    const char* ksb = reinterpret_cast<const char*>(Ks[cur]);
    const char* vsb = reinterpret_cast<const char*>(Vs[cur]);

    f32x16 sc[2] = {};
    __builtin_amdgcn_s_setprio(1);
#pragma unroll
    for (int dc = 0; dc < 8; dc++) {
#pragma unroll
      for (int kt = 0; kt < 2; kt++) {
        int kB = (((kt * 32 + l31) << 8) + dc * 32 + half * 16) ^ ((l31 & 7) << 4);
        bf16x8 kf = *reinterpret_cast<const bf16x8*>(ksb + kB);
        sc[kt] = __builtin_amdgcn_mfma_f32_32x32x16_bf16(kf, qf[dc], sc[kt], 0, 0, 0);
      }
    }
    __builtin_amdgcn_s_setprio(0);

    float pmax = -3e38f;
#pragma unroll
    for (int kt = 0; kt < 2; kt++)
#pragma unroll
      for (int r = 0; r < 16; r++) pmax = fmaxf(pmax, sc[kt][r]);
    pmax = fmaxf(pmax, __shfl_xor(pmax, 32));

    if (!__all(pmax - m_run <= 11.0f)) {
      float mn = fmaxf(m_run, pmax);
      float f = exp2f(m_run - mn);
      m_run = mn;
      l_run *= f;
#pragma unroll
      for (int idx = 0; idx < 16; idx++) {
        float fr = __shfl(f, (idx & 3) + 8 * (idx >> 2) + half * 4);
#pragma unroll
        for (int dcb = 0; dcb < 4; dcb++) acc_o[dcb][idx] *= fr;
      }
    }

    float rs = 0.f;
#pragma unroll
    for (int kt = 0; kt < 2; kt++)
#pragma unroll
      for (int r = 0; r < 16; r++) {
        float p = exp2f(sc[kt][r] - m_run);
        sc[kt][r] = p;
        rs += p;
      }
    rs += __shfl_xor(rs, 32);
    l_run += rs;

    uint pa[4][4];
#pragma unroll
    for (int skc = 0; skc < 4; skc++) {
      int kt = skc >> 1, s8 = (skc & 1) * 8;
      uint pk01 = pack_bf16(sc[kt][s8 + 0], sc[kt][s8 + 1]);
      uint pk23 = pack_bf16(sc[kt][s8 + 2], sc[kt][s8 + 3]);
      uint pk45 = pack_bf16(sc[kt][s8 + 4], sc[kt][s8 + 5]);
      uint pk67 = pack_bf16(sc[kt][s8 + 6], sc[kt][s8 + 7]);
      uint o01 = __shfl_xor(pk01, 32), o23 = __shfl_xor(pk23, 32);
      uint o45 = __shfl_xor(pk45, 32), o67 = __shfl_xor(pk67, 32);
      pa[skc][0] = half ? o45 : pk01;
      pa[skc][1] = half ? o67 : pk23;
      pa[skc][2] = half ? pk45 : o01;
      pa[skc][3] = half ? pk67 : o23;
    }

    __builtin_amdgcn_s_setprio(1);
#pragma unroll
    for (int dcb = 0; dcb < 4; dcb++) {
#pragma unroll
      for (int skc = 0; skc < 4; skc++) {
        int vB = (((dcb * 32 + l31) << 7) + skc * 32 + half * 16) ^ ((l31 & 7) << 4);
        bf16x8 vf = *reinterpret_cast<const bf16x8*>(vsb + vB);
        union { uint u[4]; bf16x8 v; } af;
        af.u[0] = pa[skc][0]; af.u[1] = pa[skc][1];
        af.u[2] = pa[skc][2]; af.u[3] = pa[skc][3];
        acc_o[dcb] = __builtin_amdgcn_mfma_f32_32x32x16_bf16(af.v, vf, acc_o[dcb], 0, 0, 0);
      }
    }
    __builtin_amdgcn_s_setprio(0);
  }

  float inv = 1.0f / l_run;
#pragma unroll
  for (int idx = 0; idx < 16; idx++) {
    int sr = (idx & 3) + 8 * (idx >> 2) + half * 4;
    float invr = __shfl(inv, sr);
    bf16* op = O + ((size_t)(sq0 + sr) * 2 + b) * 2048 + hoff + l31;
#pragma unroll
    for (int dcb = 0; dcb < 4; dcb++)
      op[dcb * 32] = (bf16)(acc_o[dcb][idx] * invr);
  }
}

extern "C" void kernel_launch(void* const* d_in, const int* in_sizes, int n_in,
                              void* d_out, int out_size, void* d_ws,
                              size_t ws_size, hipStream_t stream) {
  (void)in_sizes; (void)n_in; (void)out_size; (void)ws_size;
  const float* x  = (const float*)d_in[0];
  const float* wq = (const float*)d_in[1];
  const float* wk = (const float*)d_in[2];
  const float* wv = (const float*)d_in[3];
  const float* wo = (const float*)d_in[4];
  float* out = (float*)d_out;
  char* ws = (char*)d_ws;
  bf16* xb   = (bf16*)(ws);
  bf16* qb   = (bf16*)(ws + (1u << 24));
  bf16* kb   = (bf16*)(ws + (2u << 24));
  bf16* vt   = (bf16*)(ws + (3u << 24));
  bf16* wb   = (bf16*)(ws + (4u << 24));
  bf16* attn = xb;
  const float SCALE = 0.08838834764831845f * 1.4426950408889634f;
  const int SMEM = 3 * 49152;  // 144KB dynamic LDS for gemm_nt_256

  // defensive opt-in for >64KB dynamic LDS (no-op if already allowed)
  hipFuncSetAttribute((const void*)gemm_nt_256<bf16>,
                      hipFuncAttributeMaxDynamicSharedMemorySize, SMEM);
  hipFuncSetAttribute((const void*)gemm_nt_256<float>,
                      hipFuncAttributeMaxDynamicSharedMemorySize, SMEM);

  cast_f32_to_bf16<<<4096, 256, 0, stream>>>(x, xb, 8388608 / 8, 1.0f);

  dim3 g1(16, 16, 1);  // N/128, M/256 for M=4096
  cast_f32_to_bf16<<<2048, 256, 0, stream>>>(wq, wb, 4194304 / 8, SCALE);
  gemm_nt_256<bf16><<<g1, 512, SMEM, stream>>>(xb, wb, qb, 2048, 2048, 2048, 2048, 0, 0);

  cast_f32_to_bf16<<<2048, 256, 0, stream>>>(wk, wb, 4194304 / 8, 1.0f);
  gemm_nt_256<bf16><<<g1, 512, SMEM, stream>>>(xb, wb, kb, 2048, 2048, 2048, 2048, 0, 0);

  // V transposed, batched over b: vt[b*2048 + j][s] = sum_h wv[j][h] * x[s*2+b][h]
  cast_f32_to_bf16<<<2048, 256, 0, stream>>>(wv, wb, 4194304 / 8, 1.0f);
  dim3 g2(16, 8, 2);  // N=2048 cols /128, M=2048 rows /256, b
  gemm_nt_256<bf16><<<g2, 512, SMEM, stream>>>(wb, xb, vt, 2048, 2048, 4096, 2048,
                                               2048L, 4194304L);

  dim3 ga(32, 8);
  attn_fwd<<<ga, 512, 0, stream>>>(qb, kb, vt, attn);

  cast_f32_to_bf16<<<2048, 256, 0, stream>>>(wo, wb, 4194304 / 8, 1.0f);
  gemm_nt_256<float><<<g1, 512, SMEM, stream>>>(attn, wb, out, 2048, 2048, 2048, 2048, 0, 0);
}

// Round 4
// 272.667 us; speedup vs baseline: 1.6844x; 1.0215x over previous
//
#include <hip/hip_runtime.h>

typedef __bf16 bf16;
typedef __bf16 bf16x8 __attribute__((ext_vector_type(8)));
typedef float f32x4 __attribute__((ext_vector_type(4)));
typedef float f32x16 __attribute__((ext_vector_type(16)));
typedef unsigned int uint;

#define GLOAD16(g, l)                                                        \
  __builtin_amdgcn_global_load_lds(                                          \
      (const __attribute__((address_space(1))) void*)(g),                    \
      (__attribute__((address_space(3))) void*)(l), 16, 0, 0)

__device__ inline uint pack_bf16(float a, float b) {
  union { bf16 h[2]; uint u; } x;
  x.h[0] = (bf16)a; x.h[1] = (bf16)b;
  return x.u;
}

// ---------------- cast fp32 -> bf16 (optionally scaled) ----------------
__global__ void cast_f32_to_bf16(const float* __restrict__ in,
                                 bf16* __restrict__ out, int n8, float scale) {
  int i = blockIdx.x * blockDim.x + threadIdx.x;
  if (i >= n8) return;
  const float4* p = reinterpret_cast<const float4*>(in) + (size_t)i * 2;
  float4 a = p[0], b = p[1];
  bf16x8 o;
  o[0] = (bf16)(a.x * scale); o[1] = (bf16)(a.y * scale);
  o[2] = (bf16)(a.z * scale); o[3] = (bf16)(a.w * scale);
  o[4] = (bf16)(b.x * scale); o[5] = (bf16)(b.y * scale);
  o[6] = (bf16)(b.z * scale); o[7] = (bf16)(b.w * scale);
  *reinterpret_cast<bf16x8*>(out + (size_t)i * 8) = o;
}

// ---------------- deep-pipelined NT GEMM (unchanged r3) ----------------
template <typename OT>
__global__ __launch_bounds__(512, 2) void gemm_nt_256(
    const bf16* __restrict__ A, const bf16* __restrict__ B, OT* __restrict__ C,
    int K, int lda, int ldb, int ldc, long bsB, long bsC) {
  extern __shared__ char sh[];
  const int t = threadIdx.x;
  const int w = t >> 6, lane = t & 63;
  const int l15 = lane & 15, l4 = lane >> 4;
  const int wr = w >> 1, wc = w & 1;
  const int m0 = blockIdx.y * 256;
  const int n0 = blockIdx.x * 128;
  const bf16* Bg = B + (size_t)blockIdx.z * bsB;
  OT* Cg = C + (size_t)blockIdx.z * bsC;

  int sRow[4], sCol[4];
#pragma unroll
  for (int i = 0; i < 4; i++) {
    int sB_ = (i * 512 + t) * 16;
    int row = sB_ >> 7;
    int ge = (sB_ ^ ((row & 7) << 4)) >> 1;
    sRow[i] = ge >> 6;
    sCol[i] = ge & 63;
  }

  const int NT = K >> 6;
  f32x4 acc[4][4] = {};

  auto stage = [&](int tt) {
    char* dst = sh + (size_t)(tt % 3) * 49152;
    const int k0 = tt * 64;
#pragma unroll
    for (int i = 0; i < 4; i++)
      GLOAD16(A + (size_t)(m0 + sRow[i]) * lda + k0 + sCol[i],
              dst + (i * 512 + w * 64) * 16);
#pragma unroll
    for (int i = 0; i < 2; i++)
      GLOAD16(Bg + (size_t)(n0 + sRow[i]) * ldb + k0 + sCol[i],
              dst + 32768 + (i * 512 + w * 64) * 16);
  };

  auto compute = [&](int tt) {
    const char* Ab = sh + (size_t)(tt % 3) * 49152;
    const char* Bb = Ab + 32768;
    bf16x8 bfr[4][2];
#pragma unroll
    for (int n = 0; n < 4; n++)
#pragma unroll
      for (int kk = 0; kk < 2; kk++) {
        int row = wc * 64 + n * 16 + l15;
        int off = (row * 128 + kk * 64 + l4 * 16) ^ ((row & 7) << 4);
        bfr[n][kk] = *reinterpret_cast<const bf16x8*>(Bb + off);
      }
#pragma unroll
    for (int mh = 0; mh < 2; mh++) {
      bf16x8 af[2][2];
#pragma unroll
      for (int m = 0; m < 2; m++)
#pragma unroll
        for (int kk = 0; kk < 2; kk++) {
          int row = wr * 64 + (mh * 2 + m) * 16 + l15;
          int off = (row * 128 + kk * 64 + l4 * 16) ^ ((row & 7) << 4);
          af[m][kk] = *reinterpret_cast<const bf16x8*>(Ab + off);
        }
      __builtin_amdgcn_s_setprio(1);
#pragma unroll
      for (int m = 0; m < 2; m++)
#pragma unroll
        for (int n = 0; n < 4; n++)
#pragma unroll
          for (int kk = 0; kk < 2; kk++)
            acc[mh * 2 + m][n] = __builtin_amdgcn_mfma_f32_16x16x32_bf16(
                af[m][kk], bfr[n][kk], acc[mh * 2 + m][n], 0, 0, 0);
      __builtin_amdgcn_s_setprio(0);
    }
  };

  stage(0);
  stage(1);
  for (int tt = 0; tt < NT - 1; ++tt) {
    asm volatile("s_waitcnt vmcnt(6)" ::: "memory");
    __builtin_amdgcn_s_barrier();
    if (tt + 2 < NT) stage(tt + 2);
    compute(tt);
  }
  asm volatile("s_waitcnt vmcnt(0)" ::: "memory");
  __builtin_amdgcn_s_barrier();
  compute(NT - 1);

#pragma unroll
  for (int m = 0; m < 4; m++)
#pragma unroll
    for (int n = 0; n < 4; n++)
#pragma unroll
      for (int j = 0; j < 4; j++) {
        int row = m0 + wr * 64 + m * 16 + l4 * 4 + j;
        int col = n0 + wc * 64 + n * 16 + l15;
        Cg[(size_t)row * ldc + col] = (OT)acc[m][n][j];
      }
}

// ---------------- fused flash attention ----------------
// 256 threads (4 waves x 32 q-rows), grid (bh=32, sq_tiles=16) -> 2 blocks/CU.
// K LDS: [sk][256B row], granule ^= row&15  (2-way, free).
// V LDS: packed pairs: row' = d>>1, granule = ((d&1)*8 + sk/8) ^ (row'&15).
__global__ __launch_bounds__(256, 2) void attn_fwd(
    const bf16* __restrict__ Q, const bf16* __restrict__ Kb,
    const bf16* __restrict__ Vt, bf16* __restrict__ O) {
  __shared__ bf16 Ks[2][64 * 128];
  __shared__ bf16 Vs[2][64 * 128];
  const int t = threadIdx.x, w = t >> 6, lane = t & 63;
  const int l31 = lane & 31, half = lane >> 5;
  const int bh = blockIdx.x;
  const int b = bh >> 4, h = bh & 15;
  const int sq0 = blockIdx.y * 128 + w * 32;
  const size_t hoff = (size_t)h * 128;
  const size_t bO = (size_t)b * 2048 + hoff;

  // Q fragments (B-operand): lane holds Q[sq0+l31][dc*16 + half*8 + j]
  bf16x8 qf[8];
  {
    const bf16* qp = Q + ((size_t)(sq0 + l31) * 2 + b) * 2048 + hoff + half * 8;
#pragma unroll
    for (int dc = 0; dc < 8; dc++)
      qf[dc] = *reinterpret_cast<const bf16x8*>(qp + dc * 16);
  }

  // precomputed pre-swizzled staging sources, slot = i*256 + t
  const bf16* kp[4];
  const bf16* vp[4];
#pragma unroll
  for (int i = 0; i < 4; i++) {
    int s = i * 256 + t;
    int row = s >> 4, g = s & 15;
    int lg = g ^ (row & 15);
    kp[i] = Kb + ((size_t)row * 2 + b) * 2048 + hoff + lg * 8;  // + sk0*4096
    int d = row * 2 + (lg >> 3);
    vp[i] = Vt + (bO + d) * 2048 + (lg & 7) * 8;                // + sk0
  }

  auto stage = [&](int nb, int sk0) {
#pragma unroll
    for (int i = 0; i < 4; i++)
      GLOAD16(kp[i] + (size_t)sk0 * 4096, Ks[nb] + (i * 256 + w * 64) * 8);
#pragma unroll
    for (int i = 0; i < 4; i++)
      GLOAD16(vp[i] + sk0, Vs[nb] + (i * 256 + w * 64) * 8);
  };

  f32x16 acc_o[4] = {};
  float m_run = -3e38f, l_run = 0.f;

  stage(0, 0);

  for (int it = 0; it < 32; ++it) {
    const int cur = it & 1;
    __syncthreads();
    if (it + 1 < 32) stage(cur ^ 1, (it + 1) * 64);

    const char* ksb = reinterpret_cast<const char*>(Ks[cur]);
    const char* vsb = reinterpret_cast<const char*>(Vs[cur]);

    // ---- QK^T: S[sk][q]; A-frag K[kt*32+l31][dc*16+half*8+j] ----
    f32x16 sc[2] = {};
    __builtin_amdgcn_s_setprio(1);
#pragma unroll
    for (int dc = 0; dc < 8; dc++) {
      int kx = ((dc * 2 + half) ^ (l31 & 15)) << 4;
#pragma unroll
      for (int kt = 0; kt < 2; kt++) {
        int kB = ((kt * 32 + l31) << 8) + kx;
        bf16x8 kf = *reinterpret_cast<const bf16x8*>(ksb + kB);
        sc[kt] = __builtin_amdgcn_mfma_f32_32x32x16_bf16(kf, qf[dc], sc[kt], 0, 0, 0);
      }
    }
    __builtin_amdgcn_s_setprio(0);

    // ---- online softmax (base-2), row q = l31 in lane(+partner) ----
    float pmax = -3e38f;
#pragma unroll
    for (int kt = 0; kt < 2; kt++)
#pragma unroll
      for (int r = 0; r < 16; r++) pmax = fmaxf(pmax, sc[kt][r]);
    pmax = fmaxf(pmax, __shfl_xor(pmax, 32));

    if (!__all(pmax - m_run <= 11.0f)) {   // defer-max (T13)
      float mn = fmaxf(m_run, pmax);
      float f = exp2f(m_run - mn);
      m_run = mn;
      l_run *= f;
#pragma unroll
      for (int idx = 0; idx < 16; idx++) {
        float fr = __shfl(f, (idx & 3) + 8 * (idx >> 2) + half * 4);
#pragma unroll
        for (int dcb = 0; dcb < 4; dcb++) acc_o[dcb][idx] *= fr;
      }
    }

    float rs = 0.f;
#pragma unroll
    for (int kt = 0; kt < 2; kt++)
#pragma unroll
      for (int r = 0; r < 16; r++) {
        float p = exp2f(sc[kt][r] - m_run);
        sc[kt][r] = p;
        rs += p;
      }
    rs += __shfl_xor(rs, 32);
    l_run += rs;

    // ---- P -> A-frags via cross-half exchange ----
    uint pa[4][4];
#pragma unroll
    for (int skc = 0; skc < 4; skc++) {
      int kt = skc >> 1, s8 = (skc & 1) * 8;
      uint pk01 = pack_bf16(sc[kt][s8 + 0], sc[kt][s8 + 1]);
      uint pk23 = pack_bf16(sc[kt][s8 + 2], sc[kt][s8 + 3]);
      uint pk45 = pack_bf16(sc[kt][s8 + 4], sc[kt][s8 + 5]);
      uint pk67 = pack_bf16(sc[kt][s8 + 6], sc[kt][s8 + 7]);
      uint o01 = __shfl_xor(pk01, 32), o23 = __shfl_xor(pk23, 32);
      uint o45 = __shfl_xor(pk45, 32), o67 = __shfl_xor(pk67, 32);
      pa[skc][0] = half ? o45 : pk01;
      pa[skc][1] = half ? o67 : pk23;
      pa[skc][2] = half ? pk45 : o01;
      pa[skc][3] = half ? pk67 : o23;
    }

    // ---- PV: acc_o[dcb] += P(32q x 16sk) * V(16sk x 32d) ----
    __builtin_amdgcn_s_setprio(1);
#pragma unroll
    for (int dcb = 0; dcb < 4; dcb++) {
      int rp = dcb * 16 + (l31 >> 1);          // packed row' of d = dcb*32+l31
      int pbit = (l31 & 1) << 3;
#pragma unroll
      for (int skc = 0; skc < 4; skc++) {
        int vB = (rp << 8) + (((pbit + skc * 2 + half) ^ (l31 >> 1)) << 4);
        bf16x8 vf = *reinterpret_cast<const bf16x8*>(vsb + vB);
        union { uint u[4]; bf16x8 v; } af;
        af.u[0] = pa[skc][0]; af.u[1] = pa[skc][1];
        af.u[2] = pa[skc][2]; af.u[3] = pa[skc][3];
        acc_o[dcb] = __builtin_amdgcn_mfma_f32_32x32x16_bf16(af.v, vf, acc_o[dcb], 0, 0, 0);
      }
    }
    __builtin_amdgcn_s_setprio(0);
  }

  // ---- epilogue ----
  float inv = 1.0f / l_run;
#pragma unroll
  for (int idx = 0; idx < 16; idx++) {
    int sr = (idx & 3) + 8 * (idx >> 2) + half * 4;
    float invr = __shfl(inv, sr);
    bf16* op = O + ((size_t)(sq0 + sr) * 2 + b) * 2048 + hoff + l31;
#pragma unroll
    for (int dcb = 0; dcb < 4; dcb++)
      op[dcb * 32] = (bf16)(acc_o[dcb][idx] * invr);
  }
}

extern "C" void kernel_launch(void* const* d_in, const int* in_sizes, int n_in,
                              void* d_out, int out_size, void* d_ws,
                              size_t ws_size, hipStream_t stream) {
  (void)in_sizes; (void)n_in; (void)out_size; (void)ws_size;
  const float* x  = (const float*)d_in[0];
  const float* wq = (const float*)d_in[1];
  const float* wk = (const float*)d_in[2];
  const float* wv = (const float*)d_in[3];
  const float* wo = (const float*)d_in[4];
  float* out = (float*)d_out;
  char* ws = (char*)d_ws;
  bf16* xb   = (bf16*)(ws);
  bf16* qb   = (bf16*)(ws + (1u << 24));
  bf16* kb   = (bf16*)(ws + (2u << 24));
  bf16* vt   = (bf16*)(ws + (3u << 24));
  bf16* wb   = (bf16*)(ws + (4u << 24));
  bf16* attn = xb;
  const float SCALE = 0.08838834764831845f * 1.4426950408889634f;
  const int SMEM = 3 * 49152;

  hipFuncSetAttribute((const void*)gemm_nt_256<bf16>,
                      hipFuncAttributeMaxDynamicSharedMemorySize, SMEM);
  hipFuncSetAttribute((const void*)gemm_nt_256<float>,
                      hipFuncAttributeMaxDynamicSharedMemorySize, SMEM);

  cast_f32_to_bf16<<<4096, 256, 0, stream>>>(x, xb, 8388608 / 8, 1.0f);

  dim3 g1(16, 16, 1);
  cast_f32_to_bf16<<<2048, 256, 0, stream>>>(wq, wb, 4194304 / 8, SCALE);
  gemm_nt_256<bf16><<<g1, 512, SMEM, stream>>>(xb, wb, qb, 2048, 2048, 2048, 2048, 0, 0);

  cast_f32_to_bf16<<<2048, 256, 0, stream>>>(wk, wb, 4194304 / 8, 1.0f);
  gemm_nt_256<bf16><<<g1, 512, SMEM, stream>>>(xb, wb, kb, 2048, 2048, 2048, 2048, 0, 0);

  cast_f32_to_bf16<<<2048, 256, 0, stream>>>(wv, wb, 4194304 / 8, 1.0f);
  dim3 g2(16, 8, 2);
  gemm_nt_256<bf16><<<g2, 512, SMEM, stream>>>(wb, xb, vt, 2048, 2048, 4096, 2048,
                                               2048L, 4194304L);

  dim3 ga(32, 16);
  attn_fwd<<<ga, 256, 0, stream>>>(qb, kb, vt, attn);

  cast_f32_to_bf16<<<2048, 256, 0, stream>>>(wo, wb, 4194304 / 8, 1.0f);
  gemm_nt_256<float><<<g1, 512, SMEM, stream>>>(attn, wb, out, 2048, 2048, 2048, 2048, 0, 0);
}